// Round 1
// baseline (724.037 us; speedup 1.0000x reference)
//
#include <hip/hip_runtime.h>
#include <math.h>

#define BB 8
#define NN 512
#define DD 1024
#define HH 16
#define DH 64
#define INNER 1024
#define QKV3 3072

__device__ __forceinline__ float4 ld4(const float* p) { return *(const float4*)p; }

// ---------------------------------------------------------------------------
// Generic fp32 GEMM: C[M,Nc] = A[M,K] * W[K,Nc] (+ bias). 64x64 tile, BK=16,
// 256 threads, 4x4 acc per thread.
// ---------------------------------------------------------------------------
__global__ void gemm_f32(const float* __restrict__ A, const float* __restrict__ W,
                         float* __restrict__ C, const float* __restrict__ bias,
                         int M, int K, int Nc) {
    __shared__ float As[16][68];
    __shared__ float Bs[16][68];
    const int tid = threadIdx.x;
    const int tx = tid & 15, ty = tid >> 4;
    const int bm = blockIdx.y * 64, bn = blockIdx.x * 64;
    float acc[4][4] = {};

    for (int k0 = 0; k0 < K; k0 += 16) {
        // A tile: 64 rows x 16 k, one float4 along k per thread
        {
            int r = tid >> 2;
            int kc = (tid & 3) * 4;
            float4 a4 = ld4(A + (size_t)(bm + r) * K + k0 + kc);
            As[kc + 0][r] = a4.x; As[kc + 1][r] = a4.y;
            As[kc + 2][r] = a4.z; As[kc + 3][r] = a4.w;
        }
        // W tile: 16 k x 64 n, one float4 along n per thread
        {
            int kr = tid >> 4;
            int nc = (tid & 15) * 4;
            float4 b4 = ld4(W + (size_t)(k0 + kr) * Nc + bn + nc);
            *(float4*)&Bs[kr][nc] = b4;
        }
        __syncthreads();
#pragma unroll
        for (int kk = 0; kk < 16; ++kk) {
            float a[4], b[4];
#pragma unroll
            for (int i = 0; i < 4; ++i) a[i] = As[kk][ty * 4 + i];
#pragma unroll
            for (int j = 0; j < 4; ++j) b[j] = Bs[kk][tx * 4 + j];
#pragma unroll
            for (int i = 0; i < 4; ++i)
#pragma unroll
                for (int j = 0; j < 4; ++j) acc[i][j] += a[i] * b[j];
        }
        __syncthreads();
    }

#pragma unroll
    for (int i = 0; i < 4; ++i) {
        int row = bm + ty * 4 + i;
        float4 o;
        o.x = acc[i][0]; o.y = acc[i][1]; o.z = acc[i][2]; o.w = acc[i][3];
        if (bias) {
            o.x += bias[bn + tx * 4 + 0];
            o.y += bias[bn + tx * 4 + 1];
            o.z += bias[bn + tx * 4 + 2];
            o.w += bias[bn + tx * 4 + 3];
        }
        *(float4*)(C + (size_t)row * Nc + bn + tx * 4) = o;
    }
}

// ---------------------------------------------------------------------------
// Fused QK^T * scale + softmax.  One block per (b, h, 16-row i-tile).
// Thread (r = tid>>4, c = tid&15): row r, columns j = c + 16*t, t=0..31.
// ---------------------------------------------------------------------------
__global__ void attn_scores(const float* __restrict__ qkv, float* __restrict__ attn) {
    const int blk = blockIdx.x;
    const int it = blk & 31;          // N/16 = 32 tiles
    const int h = (blk >> 5) & 15;
    const int b = blk >> 9;
    const int i0 = it * 16;

    __shared__ float Qs[16][68];
    __shared__ float Ks[64][68];

    const int tid = threadIdx.x;
    const int r = tid >> 4;
    const int c = tid & 15;

    // Q tile: 16 rows x 64 d
    {
        int rr = tid >> 4;
        int dc = (tid & 15) * 4;
        const float* qrow = qkv + (size_t)(b * NN + i0 + rr) * QKV3 + h * DH;
        *(float4*)&Qs[rr][dc] = ld4(qrow + dc);
    }
    __syncthreads();

    float dots[32];
#pragma unroll
    for (int jt = 0; jt < 8; ++jt) {
        // K tile: 64 j x 64 d
#pragma unroll
        for (int l = 0; l < 4; ++l) {
            int idx = tid + l * 256;
            int jr = idx >> 4;
            int dc = (idx & 15) * 4;
            const float* krow = qkv + (size_t)(b * NN + jt * 64 + jr) * QKV3 + INNER + h * DH;
            *(float4*)&Ks[jr][dc] = ld4(krow + dc);
        }
        __syncthreads();
#pragma unroll
        for (int s = 0; s < 4; ++s) {
            int jl = c + 16 * s;
            float sum = 0.f;
#pragma unroll
            for (int d4 = 0; d4 < 16; ++d4) {
                float4 q4 = *(const float4*)&Qs[r][d4 * 4];
                float4 k4 = *(const float4*)&Ks[jl][d4 * 4];
                sum += q4.x * k4.x + q4.y * k4.y + q4.z * k4.z + q4.w * k4.w;
            }
            dots[jt * 4 + s] = sum * 0.125f;  // 1/sqrt(64)
        }
        __syncthreads();
    }

    // softmax across the 16 lanes of a row group + 32 regs each
    float mx = -1e30f;
#pragma unroll
    for (int t = 0; t < 32; ++t) mx = fmaxf(mx, dots[t]);
#pragma unroll
    for (int m = 1; m < 16; m <<= 1) mx = fmaxf(mx, __shfl_xor(mx, m, 64));

    float se = 0.f;
#pragma unroll
    for (int t = 0; t < 32; ++t) { dots[t] = __expf(dots[t] - mx); se += dots[t]; }
#pragma unroll
    for (int m = 1; m < 16; m <<= 1) se += __shfl_xor(se, m, 64);
    float inv = 1.f / se;

    float* arow = attn + ((size_t)((b * HH + h) * NN) + i0 + r) * NN;
#pragma unroll
    for (int t = 0; t < 32; ++t) arow[c + 16 * t] = dots[t] * inv;
}

// ---------------------------------------------------------------------------
// Re-attention (head mix) + LayerNorm over heads, in-place on attn.
// One thread per (b,i,j); owns all 16 heads.
// ---------------------------------------------------------------------------
__global__ void reattn_ln(float* __restrict__ attn, const float* __restrict__ rw,
                          const float* __restrict__ gamma, const float* __restrict__ beta) {
    __shared__ float w[16][16];
    __shared__ float gs[16], bs[16];
    const int tid = threadIdx.x;
    ((float*)w)[tid] = rw[tid];
    if (tid < 16) { gs[tid] = gamma[tid]; bs[tid] = beta[tid]; }
    __syncthreads();

    const size_t idx = (size_t)blockIdx.x * 256 + tid;  // over B*N*N
    const int j = (int)(idx & (NN - 1));
    const size_t bi = idx >> 9;
    const int i = (int)(bi & (NN - 1));
    const int b = (int)(bi >> 9);

    const size_t hstride = (size_t)NN * NN;
    float* base = attn + (size_t)b * HH * hstride + (size_t)i * NN + j;

    float vals[16];
#pragma unroll
    for (int h = 0; h < 16; ++h) vals[h] = base[h * hstride];

    float out[16];
    float mean = 0.f;
#pragma unroll
    for (int g = 0; g < 16; ++g) {
        float s = 0.f;
#pragma unroll
        for (int h = 0; h < 16; ++h) s += vals[h] * w[h][g];
        out[g] = s;
        mean += s;
    }
    mean *= (1.f / 16.f);
    float var = 0.f;
#pragma unroll
    for (int g = 0; g < 16; ++g) {
        float d = out[g] - mean;
        var += d * d;
    }
    var *= (1.f / 16.f);
    float rinv = rsqrtf(var + 1e-3f);
#pragma unroll
    for (int g = 0; g < 16; ++g)
        base[g * hstride] = (out[g] - mean) * rinv * gs[g] + bs[g];
}

// ---------------------------------------------------------------------------
// PV GEMM: out[b,i, h*64+d] = sum_j attn[b,h,i,j] * v[b,h,j,d]
// Block per (i-tile 64, b*h). 64(i) x 64(d) tile, BK=32 over j.
// ---------------------------------------------------------------------------
__global__ void pv_gemm(const float* __restrict__ attn, const float* __restrict__ qkv,
                        float* __restrict__ outh) {
    const int bh = blockIdx.y;
    const int h = bh & 15;
    const int b = bh >> 4;
    const int i0 = blockIdx.x * 64;

    __shared__ float As[32][68];  // [j][i]
    __shared__ float Vs[32][68];  // [j][d]
    const int tid = threadIdx.x;
    const int tx = tid & 15, ty = tid >> 4;
    float acc[4][4] = {};

    const float* abase = attn + (size_t)(b * HH + h) * NN * NN;
    const float* vbase = qkv + (size_t)b * NN * QKV3 + 2 * INNER + h * DH;

    for (int k0 = 0; k0 < NN; k0 += 32) {
        // attn tile 64 i x 32 j -> As[j][i]
#pragma unroll
        for (int l = 0; l < 2; ++l) {
            int idx = tid + l * 256;
            int ir = idx >> 3;
            int jc = (idx & 7) * 4;
            float4 a4 = ld4(abase + (size_t)(i0 + ir) * NN + k0 + jc);
            As[jc + 0][ir] = a4.x; As[jc + 1][ir] = a4.y;
            As[jc + 2][ir] = a4.z; As[jc + 3][ir] = a4.w;
        }
        // V tile 32 j x 64 d
#pragma unroll
        for (int l = 0; l < 2; ++l) {
            int idx = tid + l * 256;
            int jr = idx >> 4;
            int dc = (idx & 15) * 4;
            *(float4*)&Vs[jr][dc] = ld4(vbase + (size_t)(k0 + jr) * QKV3 + dc);
        }
        __syncthreads();
#pragma unroll
        for (int kk = 0; kk < 32; ++kk) {
            float a[4], v[4];
#pragma unroll
            for (int i = 0; i < 4; ++i) a[i] = As[kk][ty * 4 + i];
#pragma unroll
            for (int j = 0; j < 4; ++j) v[j] = Vs[kk][tx * 4 + j];
#pragma unroll
            for (int i = 0; i < 4; ++i)
#pragma unroll
                for (int j = 0; j < 4; ++j) acc[i][j] += a[i] * v[j];
        }
        __syncthreads();
    }

#pragma unroll
    for (int i = 0; i < 4; ++i) {
        float4 o;
        o.x = acc[i][0]; o.y = acc[i][1]; o.z = acc[i][2]; o.w = acc[i][3];
        *(float4*)(outh + (size_t)(b * NN + i0 + ty * 4 + i) * INNER + h * DH + tx * 4) = o;
    }
}

// ---------------------------------------------------------------------------
extern "C" void kernel_launch(void* const* d_in, const int* in_sizes, int n_in,
                              void* d_out, int out_size, void* d_ws, size_t ws_size,
                              hipStream_t stream) {
    const float* x        = (const float*)d_in[0];
    const float* w_qkv    = (const float*)d_in[1];
    const float* reattn_w = (const float*)d_in[2];
    const float* ln_gamma = (const float*)d_in[3];
    const float* ln_beta  = (const float*)d_in[4];
    const float* w_out    = (const float*)d_in[5];
    const float* b_out    = (const float*)d_in[6];
    float* out = (float*)d_out;

    float* qkv  = (float*)d_ws;                                 // B*N*3072
    float* attn = qkv + (size_t)BB * NN * QKV3;                  // B*H*N*N
    float* outh = attn + (size_t)BB * HH * NN * NN;              // B*N*INNER

    dim3 blk(256);
    // 1) QKV projection
    gemm_f32<<<dim3(QKV3 / 64, (BB * NN) / 64), blk, 0, stream>>>(
        x, w_qkv, qkv, nullptr, BB * NN, DD, QKV3);
    // 2) scores + softmax
    attn_scores<<<dim3(BB * HH * (NN / 16)), blk, 0, stream>>>(qkv, attn);
    // 3) re-attention + LN over heads (in-place)
    reattn_ln<<<dim3((BB * NN * NN) / 256), blk, 0, stream>>>(attn, reattn_w, ln_gamma, ln_beta);
    // 4) attn @ V -> [B,N,inner]
    pv_gemm<<<dim3(NN / 64, BB * HH), blk, 0, stream>>>(attn, qkv, outh);
    // 5) output projection + bias
    gemm_f32<<<dim3(INNER / 64, (BB * NN) / 64), blk, 0, stream>>>(
        outh, w_out, out, b_out, BB * NN, INNER, INNER);
}

// Round 2
// 389.246 us; speedup vs baseline: 1.8601x; 1.8601x over previous
//
#include <hip/hip_runtime.h>
#include <math.h>

#define BB 8
#define NN 512
#define DD 1024
#define HH 16
#define DH 64
#define INNER 1024
#define QKV3 3072

typedef __attribute__((ext_vector_type(8))) short short8;
typedef __attribute__((ext_vector_type(4))) float f32x4;

__device__ __forceinline__ float4 ld4(const float* p) { return *(const float4*)p; }

__device__ __forceinline__ unsigned short f2bf(float f) {
    unsigned u = __float_as_uint(f);
    unsigned r = (u + 0x7fffu + ((u >> 16) & 1u)) >> 16;
    return (unsigned short)r;
}

// ---------------------------------------------------------------------------
// fp32 -> bf16 elementwise convert (4 els/thread)
// ---------------------------------------------------------------------------
__global__ void conv_bf16(const float* __restrict__ in, unsigned short* __restrict__ out) {
    size_t i = ((size_t)blockIdx.x * 256 + threadIdx.x) * 4;
    float4 v = ld4(in + i);
    ushort4 o;
    o.x = f2bf(v.x); o.y = f2bf(v.y); o.z = f2bf(v.z); o.w = f2bf(v.w);
    *(ushort4*)(out + i) = o;
}

// ---------------------------------------------------------------------------
// fp32 [K][N] -> bf16 [N][K] transpose-convert, 32x32 LDS tiles
// ---------------------------------------------------------------------------
__global__ void convT_bf16(const float* __restrict__ in, unsigned short* __restrict__ out,
                           int K, int N) {
    __shared__ float t[32][33];
    const int n0 = blockIdx.x * 32, k0 = blockIdx.y * 32;
    const int tx = threadIdx.x & 31, ty = threadIdx.x >> 5;  // 32 x 8
#pragma unroll
    for (int l = 0; l < 4; ++l)
        t[ty + 8 * l][tx] = in[(size_t)(k0 + ty + 8 * l) * N + n0 + tx];
    __syncthreads();
#pragma unroll
    for (int l = 0; l < 4; ++l)
        out[(size_t)(n0 + ty + 8 * l) * K + k0 + tx] = f2bf(t[tx][ty + 8 * l]);
}

// ---------------------------------------------------------------------------
// bf16 MFMA GEMM (m97 structure): C[M,N] = A[M,K] * Bt[N,K]^T (+bias)
// 128x128 block tile, 256 threads (4 waves, 2x2 of 64x64), BK=32,
// global_load_lds width=16 staging, 16x16x32 bf16 MFMA.
// ---------------------------------------------------------------------------
__global__ __launch_bounds__(256) void gemm_bf16(
    const unsigned short* __restrict__ A, const unsigned short* __restrict__ Bt,
    float* __restrict__ C, const float* __restrict__ bias, int M, int N, int K) {
    __shared__ short As[128 * 32];
    __shared__ short Bs[128 * 32];
    const int tid = threadIdx.x;
    const int w = tid >> 6, l = tid & 63;
    const int bm = blockIdx.y * 128, bn = blockIdx.x * 128;
    const int wm = (w >> 1) * 64, wn = (w & 1) * 64;
    const int lrow = l & 15, lq = l >> 4;

    f32x4 acc[4][4];
#pragma unroll
    for (int i = 0; i < 4; ++i)
#pragma unroll
        for (int j = 0; j < 4; ++j) acc[i][j] = (f32x4){0.f, 0.f, 0.f, 0.f};

    for (int k0 = 0; k0 < K; k0 += 32) {
#pragma unroll
        for (int t = 0; t < 2; ++t) {
            const int q = w * 2 + t;
            const int li = q * 512 + l * 8;
            const int row = li >> 5, kc = li & 31;
            const unsigned short* ga = A + (size_t)(bm + row) * K + k0 + kc;
            __builtin_amdgcn_global_load_lds(
                (const __attribute__((address_space(1))) void*)ga,
                (__attribute__((address_space(3))) void*)(As + q * 512), 16, 0, 0);
            const unsigned short* gb = Bt + (size_t)(bn + row) * K + k0 + kc;
            __builtin_amdgcn_global_load_lds(
                (const __attribute__((address_space(1))) void*)gb,
                (__attribute__((address_space(3))) void*)(Bs + q * 512), 16, 0, 0);
        }
        __syncthreads();

        short8 a[4], b[4];
#pragma unroll
        for (int i = 0; i < 4; ++i)
            a[i] = *(const short8*)(As + (wm + i * 16 + lrow) * 32 + lq * 8);
#pragma unroll
        for (int j = 0; j < 4; ++j)
            b[j] = *(const short8*)(Bs + (wn + j * 16 + lrow) * 32 + lq * 8);
#pragma unroll
        for (int i = 0; i < 4; ++i)
#pragma unroll
            for (int j = 0; j < 4; ++j)
                acc[i][j] = __builtin_amdgcn_mfma_f32_16x16x32_bf16(a[i], b[j], acc[i][j], 0, 0, 0);
        __syncthreads();
    }

#pragma unroll
    for (int i = 0; i < 4; ++i)
#pragma unroll
        for (int j = 0; j < 4; ++j) {
            const int col = bn + wn + j * 16 + lrow;
            const float bv = bias ? bias[col] : 0.f;
#pragma unroll
            for (int r = 0; r < 4; ++r) {
                const int row = bm + wm + i * 16 + lq * 4 + r;
                C[(size_t)row * N + col] = acc[i][j][r] + bv;
            }
        }
}

// ---------------------------------------------------------------------------
// Fused QK^T * scale + softmax (fp32).  One block per (b, h, 16-row i-tile).
// ---------------------------------------------------------------------------
__global__ void attn_scores(const float* __restrict__ qkv, float* __restrict__ attn) {
    const int blk = blockIdx.x;
    const int it = blk & 31;
    const int h = (blk >> 5) & 15;
    const int b = blk >> 9;
    const int i0 = it * 16;

    __shared__ float Qs[16][68];
    __shared__ float Ks[64][68];

    const int tid = threadIdx.x;
    const int r = tid >> 4;
    const int c = tid & 15;

    {
        int rr = tid >> 4;
        int dc = (tid & 15) * 4;
        const float* qrow = qkv + (size_t)(b * NN + i0 + rr) * QKV3 + h * DH;
        *(float4*)&Qs[rr][dc] = ld4(qrow + dc);
    }
    __syncthreads();

    float dots[32];
#pragma unroll
    for (int jt = 0; jt < 8; ++jt) {
#pragma unroll
        for (int l = 0; l < 4; ++l) {
            int idx = tid + l * 256;
            int jr = idx >> 4;
            int dc = (idx & 15) * 4;
            const float* krow = qkv + (size_t)(b * NN + jt * 64 + jr) * QKV3 + INNER + h * DH;
            *(float4*)&Ks[jr][dc] = ld4(krow + dc);
        }
        __syncthreads();
#pragma unroll
        for (int s = 0; s < 4; ++s) {
            int jl = c + 16 * s;
            float sum = 0.f;
#pragma unroll
            for (int d4 = 0; d4 < 16; ++d4) {
                float4 q4 = *(const float4*)&Qs[r][d4 * 4];
                float4 k4 = *(const float4*)&Ks[jl][d4 * 4];
                sum += q4.x * k4.x + q4.y * k4.y + q4.z * k4.z + q4.w * k4.w;
            }
            dots[jt * 4 + s] = sum * 0.125f;
        }
        __syncthreads();
    }

    float mx = -1e30f;
#pragma unroll
    for (int t = 0; t < 32; ++t) mx = fmaxf(mx, dots[t]);
#pragma unroll
    for (int m = 1; m < 16; m <<= 1) mx = fmaxf(mx, __shfl_xor(mx, m, 64));

    float se = 0.f;
#pragma unroll
    for (int t = 0; t < 32; ++t) { dots[t] = __expf(dots[t] - mx); se += dots[t]; }
#pragma unroll
    for (int m = 1; m < 16; m <<= 1) se += __shfl_xor(se, m, 64);
    float inv = 1.f / se;

    float* arow = attn + ((size_t)((b * HH + h) * NN) + i0 + r) * NN;
#pragma unroll
    for (int t = 0; t < 32; ++t) arow[c + 16 * t] = dots[t] * inv;
}

// ---------------------------------------------------------------------------
// Re-attention (head mix) + LayerNorm over heads, in-place on attn.
// ---------------------------------------------------------------------------
__global__ void reattn_ln(float* __restrict__ attn, const float* __restrict__ rw,
                          const float* __restrict__ gamma, const float* __restrict__ beta) {
    __shared__ float w[16][16];
    __shared__ float gs[16], bs[16];
    const int tid = threadIdx.x;
    ((float*)w)[tid] = rw[tid];
    if (tid < 16) { gs[tid] = gamma[tid]; bs[tid] = beta[tid]; }
    __syncthreads();

    const size_t idx = (size_t)blockIdx.x * 256 + tid;
    const int j = (int)(idx & (NN - 1));
    const size_t bi = idx >> 9;
    const int i = (int)(bi & (NN - 1));
    const int b = (int)(bi >> 9);

    const size_t hstride = (size_t)NN * NN;
    float* base = attn + (size_t)b * HH * hstride + (size_t)i * NN + j;

    float vals[16];
#pragma unroll
    for (int h = 0; h < 16; ++h) vals[h] = base[h * hstride];

    float out[16];
    float mean = 0.f;
#pragma unroll
    for (int g = 0; g < 16; ++g) {
        float s = 0.f;
#pragma unroll
        for (int h = 0; h < 16; ++h) s += vals[h] * w[h][g];
        out[g] = s;
        mean += s;
    }
    mean *= (1.f / 16.f);
    float var = 0.f;
#pragma unroll
    for (int g = 0; g < 16; ++g) {
        float d = out[g] - mean;
        var += d * d;
    }
    var *= (1.f / 16.f);
    float rinv = rsqrtf(var + 1e-3f);
#pragma unroll
    for (int g = 0; g < 16; ++g)
        base[g * hstride] = (out[g] - mean) * rinv * gs[g] + bs[g];
}

// ---------------------------------------------------------------------------
// PV GEMM (fp32): out[b,i, h*64+d] = sum_j attn[b,h,i,j] * v[b,h,j,d]
// ---------------------------------------------------------------------------
__global__ void pv_gemm(const float* __restrict__ attn, const float* __restrict__ qkv,
                        float* __restrict__ outh) {
    const int bh = blockIdx.y;
    const int h = bh & 15;
    const int b = bh >> 4;
    const int i0 = blockIdx.x * 64;

    __shared__ float As[32][68];
    __shared__ float Vs[32][68];
    const int tid = threadIdx.x;
    const int tx = tid & 15, ty = tid >> 4;
    float acc[4][4] = {};

    const float* abase = attn + (size_t)(b * HH + h) * NN * NN;
    const float* vbase = qkv + (size_t)b * NN * QKV3 + 2 * INNER + h * DH;

    for (int k0 = 0; k0 < NN; k0 += 32) {
#pragma unroll
        for (int l = 0; l < 2; ++l) {
            int idx = tid + l * 256;
            int ir = idx >> 3;
            int jc = (idx & 7) * 4;
            float4 a4 = ld4(abase + (size_t)(i0 + ir) * NN + k0 + jc);
            As[jc + 0][ir] = a4.x; As[jc + 1][ir] = a4.y;
            As[jc + 2][ir] = a4.z; As[jc + 3][ir] = a4.w;
        }
#pragma unroll
        for (int l = 0; l < 2; ++l) {
            int idx = tid + l * 256;
            int jr = idx >> 4;
            int dc = (idx & 15) * 4;
            *(float4*)&Vs[jr][dc] = ld4(vbase + (size_t)(k0 + jr) * QKV3 + dc);
        }
        __syncthreads();
#pragma unroll
        for (int kk = 0; kk < 32; ++kk) {
            float a[4], v[4];
#pragma unroll
            for (int i = 0; i < 4; ++i) a[i] = As[kk][ty * 4 + i];
#pragma unroll
            for (int j = 0; j < 4; ++j) v[j] = Vs[kk][tx * 4 + j];
#pragma unroll
            for (int i = 0; i < 4; ++i)
#pragma unroll
                for (int j = 0; j < 4; ++j) acc[i][j] += a[i] * v[j];
        }
        __syncthreads();
    }

#pragma unroll
    for (int i = 0; i < 4; ++i) {
        float4 o;
        o.x = acc[i][0]; o.y = acc[i][1]; o.z = acc[i][2]; o.w = acc[i][3];
        *(float4*)(outh + (size_t)(b * NN + i0 + ty * 4 + i) * INNER + h * DH + tx * 4) = o;
    }
}

// ---------------------------------------------------------------------------
extern "C" void kernel_launch(void* const* d_in, const int* in_sizes, int n_in,
                              void* d_out, int out_size, void* d_ws, size_t ws_size,
                              hipStream_t stream) {
    const float* x        = (const float*)d_in[0];
    const float* w_qkv    = (const float*)d_in[1];
    const float* reattn_w = (const float*)d_in[2];
    const float* ln_gamma = (const float*)d_in[3];
    const float* ln_beta  = (const float*)d_in[4];
    const float* w_out    = (const float*)d_in[5];
    const float* b_out    = (const float*)d_in[6];
    float* out = (float*)d_out;

    float* qkv  = (float*)d_ws;                                  // B*N*3072 fp32
    float* attn = qkv + (size_t)BB * NN * QKV3;                  // B*H*N*N fp32 (128 MB)
    float* outh = attn + (size_t)BB * HH * NN * NN;              // B*N*INNER fp32

    // bf16 scratch aliased into the attn region (dead at the points of use):
    // phase A (before attn is written): xb, wqkvT
    unsigned short* xb     = (unsigned short*)attn;                       // 4.19M bf16
    unsigned short* wqkvT  = xb + (size_t)BB * NN * DD;                   // 3.15M bf16
    // phase B (after pv_gemm, attn dead): woutT, outhb
    unsigned short* woutT  = (unsigned short*)attn;                       // 1.05M bf16
    unsigned short* outhb  = woutT + (size_t)INNER * INNER;               // 4.19M bf16

    dim3 blk(256);

    // 1) converts for QKV GEMM
    conv_bf16<<<dim3((BB * NN * DD) / 1024), blk, 0, stream>>>(x, xb);
    convT_bf16<<<dim3(QKV3 / 32, DD / 32), blk, 0, stream>>>(w_qkv, wqkvT, DD, QKV3);

    // 2) QKV projection (bf16 MFMA): [4096,1024] x [1024,3072]
    gemm_bf16<<<dim3(QKV3 / 128, (BB * NN) / 128), blk, 0, stream>>>(
        xb, wqkvT, qkv, nullptr, BB * NN, QKV3, DD);

    // 3) scores + softmax (fp32)
    attn_scores<<<dim3(BB * HH * (NN / 16)), blk, 0, stream>>>(qkv, attn);

    // 4) re-attention + LN over heads (in-place)
    reattn_ln<<<dim3((BB * NN * NN) / 256), blk, 0, stream>>>(attn, reattn_w, ln_gamma, ln_beta);

    // 5) attn @ V -> [B,N,inner] (fp32)
    pv_gemm<<<dim3(NN / 64, BB * HH), blk, 0, stream>>>(attn, qkv, outh);

    // 6) converts for out projection (attn region now dead)
    conv_bf16<<<dim3((BB * NN * INNER) / 1024), blk, 0, stream>>>(outh, outhb);
    convT_bf16<<<dim3(INNER / 32, INNER / 32), blk, 0, stream>>>(w_out, woutT, INNER, INNER);

    // 7) output projection + bias (bf16 MFMA): [4096,1024] x [1024,1024]
    gemm_bf16<<<dim3(INNER / 128, (BB * NN) / 128), blk, 0, stream>>>(
        outhb, woutT, out, b_out, BB * NN, INNER, INNER);
}

// Round 3
// 247.901 us; speedup vs baseline: 2.9207x; 1.5702x over previous
//
#include <hip/hip_runtime.h>
#include <math.h>

#define BB 8
#define NN 512
#define DD 1024
#define HH 16
#define DH 64
#define INNER 1024
#define QKV3 3072

typedef __attribute__((ext_vector_type(8))) short short8;
typedef __attribute__((ext_vector_type(4))) float f32x4;

__device__ __forceinline__ float4 ld4(const float* p) { return *(const float4*)p; }

__device__ __forceinline__ unsigned short f2bf(float f) {
    unsigned u = __float_as_uint(f);
    return (unsigned short)((u + 0x7fffu + ((u >> 16) & 1u)) >> 16);
}
__device__ __forceinline__ float bf2f(unsigned short u) {
    return __uint_as_float(((unsigned)u) << 16);
}

// ---------------------------------------------------------------------------
// fp32 -> bf16 elementwise convert (4 els/thread)
// ---------------------------------------------------------------------------
__global__ void conv_bf16(const float* __restrict__ in, unsigned short* __restrict__ out) {
    size_t i = ((size_t)blockIdx.x * 256 + threadIdx.x) * 4;
    float4 v = ld4(in + i);
    ushort4 o;
    o.x = f2bf(v.x); o.y = f2bf(v.y); o.z = f2bf(v.z); o.w = f2bf(v.w);
    *(ushort4*)(out + i) = o;
}

// ---------------------------------------------------------------------------
// fp32 [K][N] -> bf16 [N][K] transpose-convert, 32x32 LDS tiles
// ---------------------------------------------------------------------------
__global__ void convT_bf16(const float* __restrict__ in, unsigned short* __restrict__ out,
                           int K, int N) {
    __shared__ float t[32][33];
    const int n0 = blockIdx.x * 32, k0 = blockIdx.y * 32;
    const int tx = threadIdx.x & 31, ty = threadIdx.x >> 5;  // 32 x 8
#pragma unroll
    for (int l = 0; l < 4; ++l)
        t[ty + 8 * l][tx] = in[(size_t)(k0 + ty + 8 * l) * N + n0 + tx];
    __syncthreads();
#pragma unroll
    for (int l = 0; l < 4; ++l)
        out[(size_t)(n0 + ty + 8 * l) * K + k0 + tx] = f2bf(t[tx][ty + 8 * l]);
}

// ---------------------------------------------------------------------------
// bf16 MFMA GEMM, fp32 out (+bias): C[M,N] = A[M,K] * Bt[N,K]^T
// ---------------------------------------------------------------------------
__global__ __launch_bounds__(256) void gemm_bf16(
    const unsigned short* __restrict__ A, const unsigned short* __restrict__ Bt,
    float* __restrict__ C, const float* __restrict__ bias, int M, int N, int K) {
    __shared__ short As[128 * 32];
    __shared__ short Bs[128 * 32];
    const int tid = threadIdx.x;
    const int w = tid >> 6, l = tid & 63;
    const int bm = blockIdx.y * 128, bn = blockIdx.x * 128;
    const int wm = (w >> 1) * 64, wn = (w & 1) * 64;
    const int lrow = l & 15, lq = l >> 4;

    f32x4 acc[4][4];
#pragma unroll
    for (int i = 0; i < 4; ++i)
#pragma unroll
        for (int j = 0; j < 4; ++j) acc[i][j] = (f32x4){0.f, 0.f, 0.f, 0.f};

    for (int k0 = 0; k0 < K; k0 += 32) {
#pragma unroll
        for (int t = 0; t < 2; ++t) {
            const int q = w * 2 + t;
            const int li = q * 512 + l * 8;
            const int row = li >> 5, kc = li & 31;
            const unsigned short* ga = A + (size_t)(bm + row) * K + k0 + kc;
            __builtin_amdgcn_global_load_lds(
                (const __attribute__((address_space(1))) void*)ga,
                (__attribute__((address_space(3))) void*)(As + q * 512), 16, 0, 0);
            const unsigned short* gb = Bt + (size_t)(bn + row) * K + k0 + kc;
            __builtin_amdgcn_global_load_lds(
                (const __attribute__((address_space(1))) void*)gb,
                (__attribute__((address_space(3))) void*)(Bs + q * 512), 16, 0, 0);
        }
        __syncthreads();

        short8 a[4], b[4];
#pragma unroll
        for (int i = 0; i < 4; ++i)
            a[i] = *(const short8*)(As + (wm + i * 16 + lrow) * 32 + lq * 8);
#pragma unroll
        for (int j = 0; j < 4; ++j)
            b[j] = *(const short8*)(Bs + (wn + j * 16 + lrow) * 32 + lq * 8);
#pragma unroll
        for (int i = 0; i < 4; ++i)
#pragma unroll
            for (int j = 0; j < 4; ++j)
                acc[i][j] = __builtin_amdgcn_mfma_f32_16x16x32_bf16(a[i], b[j], acc[i][j], 0, 0, 0);
        __syncthreads();
    }

#pragma unroll
    for (int i = 0; i < 4; ++i)
#pragma unroll
        for (int j = 0; j < 4; ++j) {
            const int col = bn + wn + j * 16 + lrow;
            const float bv = bias ? bias[col] : 0.f;
#pragma unroll
            for (int r = 0; r < 4; ++r) {
                const int row = bm + wm + i * 16 + lq * 4 + r;
                C[(size_t)row * N + col] = acc[i][j][r] + bv;
            }
        }
}

// ---------------------------------------------------------------------------
// Same GEMM but bf16 output, no bias (QKV projection)
// ---------------------------------------------------------------------------
__global__ __launch_bounds__(256) void gemm_bf16_bf(
    const unsigned short* __restrict__ A, const unsigned short* __restrict__ Bt,
    unsigned short* __restrict__ C, int M, int N, int K) {
    __shared__ short As[128 * 32];
    __shared__ short Bs[128 * 32];
    const int tid = threadIdx.x;
    const int w = tid >> 6, l = tid & 63;
    const int bm = blockIdx.y * 128, bn = blockIdx.x * 128;
    const int wm = (w >> 1) * 64, wn = (w & 1) * 64;
    const int lrow = l & 15, lq = l >> 4;

    f32x4 acc[4][4];
#pragma unroll
    for (int i = 0; i < 4; ++i)
#pragma unroll
        for (int j = 0; j < 4; ++j) acc[i][j] = (f32x4){0.f, 0.f, 0.f, 0.f};

    for (int k0 = 0; k0 < K; k0 += 32) {
#pragma unroll
        for (int t = 0; t < 2; ++t) {
            const int q = w * 2 + t;
            const int li = q * 512 + l * 8;
            const int row = li >> 5, kc = li & 31;
            const unsigned short* ga = A + (size_t)(bm + row) * K + k0 + kc;
            __builtin_amdgcn_global_load_lds(
                (const __attribute__((address_space(1))) void*)ga,
                (__attribute__((address_space(3))) void*)(As + q * 512), 16, 0, 0);
            const unsigned short* gb = Bt + (size_t)(bn + row) * K + k0 + kc;
            __builtin_amdgcn_global_load_lds(
                (const __attribute__((address_space(1))) void*)gb,
                (__attribute__((address_space(3))) void*)(Bs + q * 512), 16, 0, 0);
        }
        __syncthreads();

        short8 a[4], b[4];
#pragma unroll
        for (int i = 0; i < 4; ++i)
            a[i] = *(const short8*)(As + (wm + i * 16 + lrow) * 32 + lq * 8);
#pragma unroll
        for (int j = 0; j < 4; ++j)
            b[j] = *(const short8*)(Bs + (wn + j * 16 + lrow) * 32 + lq * 8);
#pragma unroll
        for (int i = 0; i < 4; ++i)
#pragma unroll
            for (int j = 0; j < 4; ++j)
                acc[i][j] = __builtin_amdgcn_mfma_f32_16x16x32_bf16(a[i], b[j], acc[i][j], 0, 0, 0);
        __syncthreads();
    }

#pragma unroll
    for (int i = 0; i < 4; ++i)
#pragma unroll
        for (int j = 0; j < 4; ++j) {
            const int col = bn + wn + j * 16 + lrow;
#pragma unroll
            for (int r = 0; r < 4; ++r) {
                const int row = bm + wm + i * 16 + lq * 4 + r;
                C[(size_t)row * N + col] = f2bf(acc[i][j][r]);
            }
        }
}

// ---------------------------------------------------------------------------
// Scores + softmax, MFMA, transposed-D trick: per (b,h,64 i-rows) block,
// wave w computes S^T[512 j][16 i] for i-cols w*16..+15. Lane (lrow,lq)
// holds i = i0+w*16+lrow, j = t*16+lq*4+r => full softmax row per lane
// (+shfl 16/32). XOR-swizzled LDS (row stride 128B would be 16-way conflict).
// ---------------------------------------------------------------------------
__global__ __launch_bounds__(256) void scores_mfma(
    const unsigned short* __restrict__ qkvb, unsigned short* __restrict__ attnb) {
    const int bh = blockIdx.y;
    const int h = bh & 15, b = bh >> 4;
    const int i0 = blockIdx.x * 64;
    __shared__ short Qs[64 * 64];
    __shared__ short Ks[512 * 64];
    const int tid = threadIdx.x;
    const int w = tid >> 6, l = tid & 63;
    const int lrow = l & 15, lq = l >> 4;
    const int lr8 = l >> 3;
    const int swd = ((l & 7) ^ (lr8 & 7)) * 8;  // swizzled d-offset (shorts)

    // stage K tile [512][64]: 64 chunks of 1KB (8 rows), 16 per wave
    const unsigned short* kb = qkvb + (size_t)(b * NN) * QKV3 + INNER + h * DH;
#pragma unroll
    for (int t = 0; t < 16; ++t) {
        int c = w * 16 + t;
        int j = c * 8 + lr8;
        __builtin_amdgcn_global_load_lds(
            (const __attribute__((address_space(1))) void*)(kb + (size_t)j * QKV3 + swd),
            (__attribute__((address_space(3))) void*)(Ks + c * 512), 16, 0, 0);
    }
    // stage Q tile [64][64]: 8 chunks, 2 per wave
    const unsigned short* qb = qkvb + (size_t)(b * NN + i0) * QKV3 + h * DH;
#pragma unroll
    for (int t = 0; t < 2; ++t) {
        int c = w * 2 + t;
        int r = c * 8 + lr8;
        __builtin_amdgcn_global_load_lds(
            (const __attribute__((address_space(1))) void*)(qb + (size_t)r * QKV3 + swd),
            (__attribute__((address_space(3))) void*)(Qs + c * 512), 16, 0, 0);
    }
    __syncthreads();

    // B-frag: Q cols i = w*16+lrow
    short8 qf[2];
#pragma unroll
    for (int kh = 0; kh < 2; ++kh)
        qf[kh] = *(const short8*)(Qs + (w * 16 + lrow) * 64 + (((kh * 4 + lq) ^ (lrow & 7)) * 8));

    f32x4 acc[32];
#pragma unroll
    for (int t = 0; t < 32; ++t) acc[t] = (f32x4){0.f, 0.f, 0.f, 0.f};

#pragma unroll
    for (int t = 0; t < 32; ++t) {
#pragma unroll
        for (int kh = 0; kh < 2; ++kh) {
            short8 kf = *(const short8*)(Ks + (t * 16 + lrow) * 64 + (((kh * 4 + lq) ^ (lrow & 7)) * 8));
            acc[t] = __builtin_amdgcn_mfma_f32_16x16x32_bf16(kf, qf[kh], acc[t], 0, 0, 0);
        }
    }

    // softmax: lane owns row i; values j = t*16 + lq*4 + r
    float mx = -1e30f;
#pragma unroll
    for (int t = 0; t < 32; ++t)
#pragma unroll
        for (int r = 0; r < 4; ++r) mx = fmaxf(mx, acc[t][r]);
    mx = fmaxf(mx, __shfl_xor(mx, 16, 64));
    mx = fmaxf(mx, __shfl_xor(mx, 32, 64));

    float se = 0.f;
#pragma unroll
    for (int t = 0; t < 32; ++t)
#pragma unroll
        for (int r = 0; r < 4; ++r) {
            float e = __expf((acc[t][r] - mx) * 0.125f);
            acc[t][r] = e;
            se += e;
        }
    se += __shfl_xor(se, 16, 64);
    se += __shfl_xor(se, 32, 64);
    const float inv = 1.f / se;

    unsigned short* orow = attnb + ((size_t)bh * NN + i0 + w * 16 + lrow) * NN + lq * 4;
#pragma unroll
    for (int t = 0; t < 32; ++t) {
        ushort4 o;
        o.x = f2bf(acc[t][0] * inv); o.y = f2bf(acc[t][1] * inv);
        o.z = f2bf(acc[t][2] * inv); o.w = f2bf(acc[t][3] * inv);
        *(ushort4*)(orow + t * 16) = o;
    }
}

// ---------------------------------------------------------------------------
// Re-attention + LN over heads, bf16 in/out (fp32 math), 2 j per thread
// ---------------------------------------------------------------------------
__global__ void reattn_ln_bf(unsigned short* __restrict__ attnb,
                             const float* __restrict__ rw,
                             const float* __restrict__ gamma,
                             const float* __restrict__ beta) {
    __shared__ float w[16][16];
    __shared__ float gs[16], bs[16];
    const int tid = threadIdx.x;
    ((float*)w)[tid] = rw[tid];
    if (tid < 16) { gs[tid] = gamma[tid]; bs[tid] = beta[tid]; }
    __syncthreads();

    const size_t idx = (size_t)blockIdx.x * 256 + tid;  // over B*N*N/2
    const int j2 = (int)(idx & 255);
    const int i = (int)((idx >> 8) & 511);
    const int b = (int)(idx >> 17);
    const size_t hstr = (size_t)NN * NN;
    unsigned short* base = attnb + (size_t)b * HH * hstr + (size_t)i * NN + j2 * 2;

    float vx[16], vy[16];
#pragma unroll
    for (int h = 0; h < 16; ++h) {
        ushort2 u = *(const ushort2*)(base + h * hstr);
        vx[h] = bf2f(u.x); vy[h] = bf2f(u.y);
    }
    float ox[16], oy[16];
    float mex = 0.f, mey = 0.f;
#pragma unroll
    for (int g = 0; g < 16; ++g) {
        float sx = 0.f, sy = 0.f;
#pragma unroll
        for (int h = 0; h < 16; ++h) { sx += vx[h] * w[h][g]; sy += vy[h] * w[h][g]; }
        ox[g] = sx; oy[g] = sy; mex += sx; mey += sy;
    }
    mex *= 0.0625f; mey *= 0.0625f;
    float vax = 0.f, vay = 0.f;
#pragma unroll
    for (int g = 0; g < 16; ++g) {
        float dx = ox[g] - mex, dy = oy[g] - mey;
        vax += dx * dx; vay += dy * dy;
    }
    const float rx = rsqrtf(vax * 0.0625f + 1e-3f);
    const float ry = rsqrtf(vay * 0.0625f + 1e-3f);
#pragma unroll
    for (int g = 0; g < 16; ++g) {
        ushort2 o;
        o.x = f2bf((ox[g] - mex) * rx * gs[g] + bs[g]);
        o.y = f2bf((oy[g] - mey) * ry * gs[g] + bs[g]);
        *(ushort2*)(base + g * hstr) = o;
    }
}

// ---------------------------------------------------------------------------
// V transpose: qkvb [b,j,2048+h*64+d] -> vT [bh, d, j] (bf16)
// ---------------------------------------------------------------------------
__global__ void transpose_v(const unsigned short* __restrict__ qkvb,
                            unsigned short* __restrict__ vT) {
    __shared__ unsigned short t[32][33];
    const int bh = blockIdx.z;
    const int h = bh & 15, b = bh >> 4;
    const int j0 = blockIdx.x * 32, d0 = blockIdx.y * 32;
    const int tx = threadIdx.x & 31, ty = threadIdx.x >> 5;
    const unsigned short* src = qkvb + (size_t)(b * NN) * QKV3 + 2 * INNER + h * DH;
#pragma unroll
    for (int k = 0; k < 4; ++k)
        t[ty + 8 * k][tx] = src[(size_t)(j0 + ty + 8 * k) * QKV3 + d0 + tx];
    __syncthreads();
    unsigned short* dst = vT + (size_t)bh * DH * NN;
#pragma unroll
    for (int k = 0; k < 4; ++k)
        dst[(size_t)(d0 + ty + 8 * k) * NN + j0 + tx] = t[tx][ty + 8 * k];
}

// ---------------------------------------------------------------------------
// PV MFMA: outh[b,i,h*64+d] = sum_j P[bh,i,j] V[bh,j,d], P bf16, vT bf16.
// Transposed-D: lane holds col i, rows d -> ushort4 stores along d.
// ---------------------------------------------------------------------------
__global__ __launch_bounds__(256) void pv_mfma(
    const unsigned short* __restrict__ attnb, const unsigned short* __restrict__ vT,
    unsigned short* __restrict__ outhb) {
    const int bh = blockIdx.y;
    const int h = bh & 15, b = bh >> 4;
    const int i0 = blockIdx.x * 128;
    __shared__ short Ps[128 * 64];
    __shared__ short Vs[64 * 64];
    const int tid = threadIdx.x;
    const int w = tid >> 6, l = tid & 63;
    const int lrow = l & 15, lq = l >> 4;
    const int lr8 = l >> 3;
    const int swd = ((l & 7) ^ (lr8 & 7)) * 8;

    f32x4 acc[2][4];
#pragma unroll
    for (int ic = 0; ic < 2; ++ic)
#pragma unroll
        for (int dt = 0; dt < 4; ++dt) acc[ic][dt] = (f32x4){0.f, 0.f, 0.f, 0.f};

    const unsigned short* pb = attnb + ((size_t)bh * NN + i0) * NN;
    const unsigned short* vb = vT + (size_t)bh * DH * NN;

    for (int j0 = 0; j0 < NN; j0 += 64) {
#pragma unroll
        for (int t = 0; t < 4; ++t) {
            int c = w * 4 + t;
            int r = c * 8 + lr8;
            __builtin_amdgcn_global_load_lds(
                (const __attribute__((address_space(1))) void*)(pb + (size_t)r * NN + j0 + swd),
                (__attribute__((address_space(3))) void*)(Ps + c * 512), 16, 0, 0);
        }
#pragma unroll
        for (int t = 0; t < 2; ++t) {
            int c = w * 2 + t;
            int d = c * 8 + lr8;
            __builtin_amdgcn_global_load_lds(
                (const __attribute__((address_space(1))) void*)(vb + (size_t)d * NN + j0 + swd),
                (__attribute__((address_space(3))) void*)(Vs + c * 512), 16, 0, 0);
        }
        __syncthreads();

#pragma unroll
        for (int kh = 0; kh < 2; ++kh) {
            short8 vf[4];
#pragma unroll
            for (int dt = 0; dt < 4; ++dt)
                vf[dt] = *(const short8*)(Vs + (dt * 16 + lrow) * 64 + (((kh * 4 + lq) ^ (lrow & 7)) * 8));
#pragma unroll
            for (int ic = 0; ic < 2; ++ic) {
                short8 pf = *(const short8*)(Ps + (w * 32 + ic * 16 + lrow) * 64 + (((kh * 4 + lq) ^ (lrow & 7)) * 8));
#pragma unroll
                for (int dt = 0; dt < 4; ++dt)
                    acc[ic][dt] = __builtin_amdgcn_mfma_f32_16x16x32_bf16(vf[dt], pf, acc[ic][dt], 0, 0, 0);
            }
        }
        __syncthreads();
    }

#pragma unroll
    for (int ic = 0; ic < 2; ++ic) {
        unsigned short* orow = outhb +
            ((size_t)(b * NN + i0 + w * 32 + ic * 16 + lrow)) * INNER + h * DH + lq * 4;
#pragma unroll
        for (int dt = 0; dt < 4; ++dt) {
            ushort4 o;
            o.x = f2bf(acc[ic][dt][0]); o.y = f2bf(acc[ic][dt][1]);
            o.z = f2bf(acc[ic][dt][2]); o.w = f2bf(acc[ic][dt][3]);
            *(ushort4*)(orow + dt * 16) = o;
        }
    }
}

// ---------------------------------------------------------------------------
extern "C" void kernel_launch(void* const* d_in, const int* in_sizes, int n_in,
                              void* d_out, int out_size, void* d_ws, size_t ws_size,
                              hipStream_t stream) {
    const float* x        = (const float*)d_in[0];
    const float* w_qkv    = (const float*)d_in[1];
    const float* reattn_w = (const float*)d_in[2];
    const float* ln_gamma = (const float*)d_in[3];
    const float* ln_beta  = (const float*)d_in[4];
    const float* w_out    = (const float*)d_in[5];
    const float* b_out    = (const float*)d_in[6];
    float* out = (float*)d_out;

    unsigned short* qkvb  = (unsigned short*)d_ws;                 // 12.58M
    unsigned short* attnb = qkvb + (size_t)BB * NN * QKV3;         // 33.55M
    unsigned short* vTb   = attnb + (size_t)BB * HH * NN * NN;     // 4.19M
    unsigned short* outhb = vTb + (size_t)BB * HH * DH * NN;       // 4.19M
    unsigned short* xb    = outhb + (size_t)BB * NN * INNER;       // 4.19M
    unsigned short* wqkvT = xb + (size_t)BB * NN * DD;             // 3.15M
    unsigned short* woutT = wqkvT + (size_t)DD * QKV3;             // 1.05M

    dim3 blk(256);

    conv_bf16<<<dim3((BB * NN * DD) / 1024), blk, 0, stream>>>(x, xb);
    convT_bf16<<<dim3(QKV3 / 32, DD / 32), blk, 0, stream>>>(w_qkv, wqkvT, DD, QKV3);
    convT_bf16<<<dim3(INNER / 32, INNER / 32), blk, 0, stream>>>(w_out, woutT, INNER, INNER);

    // QKV projection -> bf16
    gemm_bf16_bf<<<dim3(QKV3 / 128, (BB * NN) / 128), blk, 0, stream>>>(
        xb, wqkvT, qkvb, BB * NN, QKV3, DD);

    // scores + softmax -> attn bf16
    scores_mfma<<<dim3(NN / 64, BB * HH), blk, 0, stream>>>(qkvb, attnb);

    // re-attention + LN (in-place bf16)
    reattn_ln_bf<<<dim3((BB * NN * NN) / 512), blk, 0, stream>>>(attnb, reattn_w, ln_gamma, ln_beta);

    // V transpose -> [bh][d][j]
    transpose_v<<<dim3(NN / 32, DH / 32, BB * HH), blk, 0, stream>>>(qkvb, vTb);

    // P @ V -> outh bf16
    pv_mfma<<<dim3(NN / 128, BB * HH), blk, 0, stream>>>(attnb, vTb, outhb);

    // output projection + bias (fp32 out)
    gemm_bf16<<<dim3(INNER / 128, (BB * NN) / 128), blk, 0, stream>>>(
        outhb, woutT, out, b_out, BB * NN, INNER, INNER);
}